// Round 7
// baseline (1361.824 us; speedup 1.0000x reference)
//
#include <hip/hip_runtime.h>
#include <hip/hip_bf16.h>
#include <hip/hip_cooperative_groups.h>
#include <math.h>

namespace cg = cooperative_groups;

#define SEQ 2048
#define BATCH 4
#define HDIM 256
#define NHEAD 4
#define FFN_DIM 1024
#define MTOT (BATCH*SEQ)   // 8192
#define WIN 32

typedef __attribute__((ext_vector_type(8))) short bf16x8;
typedef __attribute__((ext_vector_type(4))) float f32x4;

// ===========================================================================
// Shared device helpers
// ===========================================================================
__device__ __forceinline__ void cvt_item(size_t e,
    const float* w_in, const float* w_out, const float* qkv_w, const float* out_w,
    const float* ff1_w, const float* ff2_w, const float* x,
    __hip_bfloat16* wb, __hip_bfloat16* xb)
{
    const float* src;
    __hip_bfloat16* dst;
    if (e < 720896) {
        if (e < 65536)       { src = w_in  + e;            dst = wb + e; }
        else if (e < 131072) { src = w_out + (e - 65536);  dst = wb + e; }
        else                 { src = qkv_w + (e - 131072); dst = wb + e; }
    } else if (e < 917504)   { src = out_w + (e - 720896); dst = wb + e; }
    else if (e < 1703936)    { src = ff1_w + (e - 917504); dst = wb + e; }
    else if (e < 2490368)    { src = ff2_w + (e - 1703936); dst = wb + e; }
    else                     { src = x + (e - 2490368);    dst = xb + (e - 2490368); }
    const float4* s4 = (const float4*)src;
    float4 a = s4[0], b = s4[1];
    union { bf16x8 v; __hip_bfloat16 el[8]; } u;
    u.el[0] = __float2bfloat16(a.x); u.el[1] = __float2bfloat16(a.y);
    u.el[2] = __float2bfloat16(a.z); u.el[3] = __float2bfloat16(a.w);
    u.el[4] = __float2bfloat16(b.x); u.el[5] = __float2bfloat16(b.y);
    u.el[6] = __float2bfloat16(b.z); u.el[7] = __float2bfloat16(b.w);
    *(bf16x8*)dst = u.v;
}

// 64x64 tile GEMM core: 4 waves (wm,wn in {0,1}), wave tile 32x32.
// rowBase/colBase already include wm*32 / wn*32.
__device__ __forceinline__ void gemm_core(const short* __restrict__ A,
                                          const short* __restrict__ W,
                                          int lda, int ldw, int K,
                                          int rowBase, int colBase, int lane,
                                          f32x4 acc[2][2])
{
    int lr = lane & 15, hi = lane >> 4;
    const short* pa = A + (size_t)(rowBase + lr) * lda + hi * 8;
    const short* pb = W + (size_t)(colBase + lr) * ldw + hi * 8;
    acc[0][0] = (f32x4){0.f,0.f,0.f,0.f}; acc[0][1] = (f32x4){0.f,0.f,0.f,0.f};
    acc[1][0] = (f32x4){0.f,0.f,0.f,0.f}; acc[1][1] = (f32x4){0.f,0.f,0.f,0.f};
    for (int k0 = 0; k0 < K; k0 += 32) {
        bf16x8 a0 = *(const bf16x8*)pa;
        bf16x8 a1 = *(const bf16x8*)(pa + (size_t)16 * lda);
        bf16x8 b0 = *(const bf16x8*)pb;
        bf16x8 b1 = *(const bf16x8*)(pb + (size_t)16 * ldw);
        acc[0][0] = __builtin_amdgcn_mfma_f32_16x16x32_bf16(a0, b0, acc[0][0], 0,0,0);
        acc[0][1] = __builtin_amdgcn_mfma_f32_16x16x32_bf16(a0, b1, acc[0][1], 0,0,0);
        acc[1][0] = __builtin_amdgcn_mfma_f32_16x16x32_bf16(a1, b0, acc[1][0], 0,0,0);
        acc[1][1] = __builtin_amdgcn_mfma_f32_16x16x32_bf16(a1, b1, acc[1][1], 0,0,0);
        pa += 32; pb += 32;
    }
}

// wave-per-row LN over 4 rows: h fp32 row -> bf16 row of o.
__device__ __forceinline__ void ln_stage(const float* __restrict__ h,
                                         const float* __restrict__ g,
                                         const float* __restrict__ b,
                                         __hip_bfloat16* __restrict__ o,
                                         int bid, int wave, int lane)
{
    float4 gv = *(const float4*)(g + lane * 4);
    float4 bv = *(const float4*)(b + lane * 4);
    #pragma unroll
    for (int rr = 0; rr < 4; rr++) {
        int row = bid * 32 + wave * 4 + rr;
        float4 xv = *(const float4*)(h + (size_t)row * HDIM + lane * 4);
        float s = xv.x + xv.y + xv.z + xv.w;
        #pragma unroll
        for (int off = 32; off >= 1; off >>= 1) s += __shfl_xor(s, off);
        float mu = s * (1.0f / 256.0f);
        float d0 = xv.x - mu, d1 = xv.y - mu, d2 = xv.z - mu, d3 = xv.w - mu;
        float v = d0*d0 + d1*d1 + d2*d2 + d3*d3;
        #pragma unroll
        for (int off = 32; off >= 1; off >>= 1) v += __shfl_xor(v, off);
        float rstd = rsqrtf(v * (1.0f / 256.0f) + 1e-5f);
        union { short e[4]; uint2 w2; } ov;
        ov.e[0] = (short)__bfloat16_as_ushort(__float2bfloat16(d0*rstd*gv.x + bv.x));
        ov.e[1] = (short)__bfloat16_as_ushort(__float2bfloat16(d1*rstd*gv.y + bv.y));
        ov.e[2] = (short)__bfloat16_as_ushort(__float2bfloat16(d2*rstd*gv.z + bv.z));
        ov.e[3] = (short)__bfloat16_as_ushort(__float2bfloat16(d3*rstd*gv.w + bv.w));
        *(uint2*)((short*)o + (size_t)row * HDIM + lane * 4) = ov.w2;
    }
}

struct AttnLDS {
    __align__(16) __hip_bfloat16 Vt[64][128];
    __align__(16) __hip_bfloat16 Pl[32][96];
    float sm[2][32], ss[2][32];
};

// One 32-query banded-attention tile (exact softmax; band fits in tile).
// Executed by a 4-wave group (w4 = wave index in group, ltid = tid in group).
__device__ __forceinline__ void attn_tile(const short* __restrict__ qkvd,
                                          __hip_bfloat16* __restrict__ o,
                                          int bh, int i0, AttnLDS& S,
                                          int w4, int lane, int ltid)
{
    int qh = w4 & 1, seg = w4 >> 1;
    int klo = i0 - 32;
    const short* Qd = qkvd + (size_t)bh * 131072;
    const short* Kd = Qd + 2097152;
    const short* Vd = Qd + 4194304;

    { // stage V^T (coalesced 16B reads, swizzled scalar writes)
        int m = ltid & 7, rlane = ltid >> 3, dpart = m * 8;
        #pragma unroll
        for (int rr = 0; rr < 3; rr++) {
            int row = rr * 32 + rlane;
            int j = klo + row;
            j = j < 0 ? 0 : (j > SEQ - 1 ? SEQ - 1 : j);
            union { bf16x8 v; short e[8]; } u;
            u.v = *(const bf16x8*)(Vd + (size_t)j * 64 + dpart);
            int colp = row ^ (m << 3);
            #pragma unroll
            for (int jj = 0; jj < 8; jj++)
                *(short*)&S.Vt[dpart + jj][colp] = u.e[jj];
        }
    }

    int lr = lane & 15, hi = lane >> 4;
    int cc = lane & 15, quad = lane >> 4;
    int qoff = qh * 16 + quad * 4;

    bf16x8 qf[2];
    #pragma unroll
    for (int ds = 0; ds < 2; ds++)
        qf[ds] = *(const bf16x8*)(Qd + (size_t)(i0 + qh * 16 + lr) * 64 + ds * 32 + hi * 8);
    f32x4 sacc[3];
    #pragma unroll
    for (int t = 0; t < 3; t++) {
        int j = klo + seg * 48 + t * 16 + lr;
        j = j < 0 ? 0 : (j > SEQ - 1 ? SEQ - 1 : j);
        const short* kp = Kd + (size_t)j * 64 + hi * 8;
        bf16x8 k0 = *(const bf16x8*)kp;
        bf16x8 k1 = *(const bf16x8*)(kp + 32);
        f32x4 a = (f32x4){0.f,0.f,0.f,0.f};
        a = __builtin_amdgcn_mfma_f32_16x16x32_bf16(qf[0], k0, a, 0,0,0);
        a = __builtin_amdgcn_mfma_f32_16x16x32_bf16(qf[1], k1, a, 0,0,0);
        sacc[t] = a;
    }

    float s[3][4];
    #pragma unroll
    for (int t = 0; t < 3; t++) {
        int koff = seg * 48 + t * 16 + cc;
        int jj = klo + koff;
        #pragma unroll
        for (int r = 0; r < 4; r++) {
            int rel = koff - (qoff + r);
            bool ok = (jj >= 0) && (jj < SEQ) && (rel >= 0) && (rel <= 64);
            s[t][r] = ok ? sacc[t][r] * 0.125f : -1e30f;
        }
    }

    float mrow[4], srow[4];
    #pragma unroll
    for (int r = 0; r < 4; r++)
        mrow[r] = fmaxf(fmaxf(s[0][r], s[1][r]), s[2][r]);
    #pragma unroll
    for (int off = 8; off >= 1; off >>= 1)
        #pragma unroll
        for (int r = 0; r < 4; r++)
            mrow[r] = fmaxf(mrow[r], __shfl_xor(mrow[r], off));
    #pragma unroll
    for (int r = 0; r < 4; r++)
        srow[r] = __expf(s[0][r]-mrow[r]) + __expf(s[1][r]-mrow[r]) + __expf(s[2][r]-mrow[r]);
    #pragma unroll
    for (int off = 8; off >= 1; off >>= 1)
        #pragma unroll
        for (int r = 0; r < 4; r++)
            srow[r] += __shfl_xor(srow[r], off);
    if (cc == 0) {
        #pragma unroll
        for (int r = 0; r < 4; r++) { S.sm[seg][qoff+r] = mrow[r]; S.ss[seg][qoff+r] = srow[r]; }
    }
    __syncthreads();

    float Mr[4], inv[4];
    #pragma unroll
    for (int r = 0; r < 4; r++) {
        float m0 = S.sm[0][qoff+r], m1 = S.sm[1][qoff+r];
        float M = fmaxf(m0, m1);
        float dn = S.ss[0][qoff+r] * __expf(m0 - M) + S.ss[1][qoff+r] * __expf(m1 - M);
        Mr[r] = M; inv[r] = 1.0f / dn;
    }
    #pragma unroll
    for (int t = 0; t < 3; t++)
        #pragma unroll
        for (int r = 0; r < 4; r++)
            S.Pl[qoff+r][seg*48 + t*16 + cc] = __float2bfloat16(__expf(s[t][r]-Mr[r]) * inv[r]);
    __syncthreads();

    f32x4 oacc[2];
    oacc[0] = (f32x4){0.f,0.f,0.f,0.f}; oacc[1] = (f32x4){0.f,0.f,0.f,0.f};
    #pragma unroll
    for (int ks = 0; ks < 3; ks++) {
        int kk = ks * 32;
        bf16x8 pf = *(const bf16x8*)&S.Pl[qh*16 + lr][kk + hi*8];
        #pragma unroll
        for (int dt = 0; dt < 2; dt++) {
            int d = seg*32 + dt*16 + lr;
            int colb = (kk + hi*8) ^ (((d >> 3) & 7) << 3);
            bf16x8 vf = *(const bf16x8*)&S.Vt[d][colb];
            oacc[dt] = __builtin_amdgcn_mfma_f32_16x16x32_bf16(pf, vf, oacc[dt], 0,0,0);
        }
    }
    int b = bh >> 2, hd = bh & 3;
    #pragma unroll
    for (int dt = 0; dt < 2; dt++) {
        int col = hd*64 + seg*32 + dt*16 + cc;
        #pragma unroll
        for (int r = 0; r < 4; r++) {
            int row = b * SEQ + i0 + qoff + r;
            o[(size_t)row * HDIM + col] = __float2bfloat16(oacc[dt][r]);
        }
    }
}

// ===========================================================================
// MEGA KERNEL: whole forward pass, 256 blocks x 512 threads, cooperative.
// ===========================================================================
__global__ __launch_bounds__(512)
void mega(const float* x, const float* w_in, const float* w_out, const float* b_out,
          const float* qkv_w, const float* qkv_b, const float* out_w, const float* out_b,
          const float* ln1_g, const float* ln1_b, const float* ln2_g, const float* ln2_b,
          const float* ff1_w, const float* ff1_b, const float* ff2_w, const float* ff2_b,
          const float* lnf_g, const float* lnf_b, float* dout, char* ws)
{
    cg::grid_group grid = cg::this_grid();
    __shared__ AttnLDS asl[2];

    float*          h    = (float*)ws;                        // 8 MB
    __hip_bfloat16* xn   = (__hip_bfloat16*)(ws + 8388608);   // 4 MB
    short*          qkvd = (short*)(ws + 12582912);           // 12 MB head-split Q|K|V
    __hip_bfloat16* att  = (__hip_bfloat16*)(ws + 25165824);  // 4 MB
    __hip_bfloat16* ffb  = (__hip_bfloat16*)(ws + 29360128);  // 16 MB
    __hip_bfloat16* wb   = (__hip_bfloat16*)(ws + 46137344);  // ~5 MB weights
    __hip_bfloat16* xb   = (__hip_bfloat16*)(ws + 51118080);  // 4 MB

    const int bid = blockIdx.x, tid = threadIdx.x;
    const int wave = tid >> 6, lane = tid & 63;
    const int grp = wave >> 2, w4 = wave & 3;
    const int wm = w4 >> 1, wn = w4 & 1;
    const int ltid = tid & 255;
    const int cc = lane & 15, quad = lane >> 4;

    // ---- S0: convert weights + x to bf16 ----
    for (int i = bid * 512 + tid; i < 573440; i += 131072)
        cvt_item((size_t)i * 8, w_in, w_out, qkv_w, out_w, ff1_w, ff2_w, x, wb, xb);
    grid.sync();

    // ---- S1: embed  h = 16*(xb @ w_in^T) + PE  (512 tiles, 1 round) ----
    {
        int t = bid * 2 + grp;
        int rB = (t >> 2) * 64 + wm * 32, cB = (t & 3) * 64 + wn * 32;
        f32x4 acc[2][2];
        gemm_core((const short*)xb, (const short*)wb, HDIM, HDIM, HDIM, rB, cB, lane, acc);
        #pragma unroll
        for (int mt = 0; mt < 2; mt++)
            #pragma unroll
            for (int nt = 0; nt < 2; nt++) {
                int col = cB + nt*16 + cc;
                int i2 = col & ~1;
                float freq = __expf((float)i2 * (-9.210340371976184f / 256.0f));
                #pragma unroll
                for (int r = 0; r < 4; r++) {
                    int row = rB + mt*16 + quad*4 + r;
                    float arg = (float)(row & (SEQ-1)) * freq;
                    float pe = (col & 1) ? __cosf(arg) : __sinf(arg);
                    h[(size_t)row * HDIM + col] = 16.0f * acc[mt][nt][r] + pe;
                }
            }
    }
    grid.sync();

    for (int l = 0; l < 3; l++) {
        const short* qw = (const short*)(wb + 131072)  + (size_t)l * 768 * HDIM;
        const short* ow = (const short*)(wb + 720896)  + (size_t)l * HDIM * HDIM;
        const short* f1 = (const short*)(wb + 917504)  + (size_t)l * FFN_DIM * HDIM;
        const short* f2 = (const short*)(wb + 1703936) + (size_t)l * HDIM * FFN_DIM;

        // LN1
        ln_stage(h, ln1_g + l*HDIM, ln1_b + l*HDIM, xn, bid, wave, lane);
        grid.sync();

        // qkv: 1536 tiles, 3 rounds; head-split epilogue
        for (int rnd = 0; rnd < 3; rnd++) {
            int t = bid * 6 + rnd * 2 + grp;
            int rB = (t / 12) * 64 + wm * 32, cB = (t % 12) * 64 + wn * 32;
            f32x4 acc[2][2];
            gemm_core((const short*)xn, qw, HDIM, HDIM, HDIM, rB, cB, lane, acc);
            #pragma unroll
            for (int mt = 0; mt < 2; mt++)
                #pragma unroll
                for (int nt = 0; nt < 2; nt++) {
                    int col = cB + nt*16 + cc;
                    float bv = qkv_b[l*768 + col];
                    int sec = col >> 8, hd = (col >> 6) & 3, d = col & 63;
                    #pragma unroll
                    for (int r = 0; r < 4; r++) {
                        int row = rB + mt*16 + quad*4 + r;
                        size_t idx = (size_t)sec * 2097152
                                   + (size_t)(((row >> 11) << 2) | hd) * 131072
                                   + (size_t)(row & (SEQ-1)) * 64 + d;
                        ((__hip_bfloat16*)qkvd)[idx] = __float2bfloat16(acc[mt][nt][r] + bv);
                    }
                }
        }
        grid.sync();

        // attn: 1024 tiles, 2 rounds x 2 groups
        for (int rnd = 0; rnd < 2; rnd++) {
            int at = bid * 4 + rnd * 2 + grp;
            attn_tile(qkvd, att, at >> 6, (at & 63) * 32, asl[grp], w4, lane, ltid);
            __syncthreads();
        }
        grid.sync();

        // proj: h += att @ out_w^T + out_b   (512 tiles, 1 round)
        {
            int t = bid * 2 + grp;
            int rB = (t >> 2) * 64 + wm * 32, cB = (t & 3) * 64 + wn * 32;
            f32x4 acc[2][2];
            gemm_core((const short*)att, ow, HDIM, HDIM, HDIM, rB, cB, lane, acc);
            #pragma unroll
            for (int mt = 0; mt < 2; mt++)
                #pragma unroll
                for (int nt = 0; nt < 2; nt++) {
                    int col = cB + nt*16 + cc;
                    float bv = out_b[l*HDIM + col];
                    #pragma unroll
                    for (int r = 0; r < 4; r++) {
                        int row = rB + mt*16 + quad*4 + r;
                        h[(size_t)row * HDIM + col] += acc[mt][nt][r] + bv;
                    }
                }
        }
        grid.sync();

        // LN2
        ln_stage(h, ln2_g + l*HDIM, ln2_b + l*HDIM, xn, bid, wave, lane);
        grid.sync();

        // ff1: ffb = relu(xn @ ff1_w^T + b)  (2048 tiles, 4 rounds)
        for (int rnd = 0; rnd < 4; rnd++) {
            int t = bid * 8 + rnd * 2 + grp;
            int rB = (t >> 4) * 64 + wm * 32, cB = (t & 15) * 64 + wn * 32;
            f32x4 acc[2][2];
            gemm_core((const short*)xn, f1, HDIM, HDIM, HDIM, rB, cB, lane, acc);
            #pragma unroll
            for (int mt = 0; mt < 2; mt++)
                #pragma unroll
                for (int nt = 0; nt < 2; nt++) {
                    int col = cB + nt*16 + cc;
                    float bv = ff1_b[l*FFN_DIM + col];
                    #pragma unroll
                    for (int r = 0; r < 4; r++) {
                        int row = rB + mt*16 + quad*4 + r;
                        ffb[(size_t)row * FFN_DIM + col] =
                            __float2bfloat16(fmaxf(acc[mt][nt][r] + bv, 0.f));
                    }
                }
        }
        grid.sync();

        // ff2: h += ffb @ ff2_w^T + b  (512 tiles, K=1024, 1 round)
        {
            int t = bid * 2 + grp;
            int rB = (t >> 2) * 64 + wm * 32, cB = (t & 3) * 64 + wn * 32;
            f32x4 acc[2][2];
            gemm_core((const short*)ffb, f2, FFN_DIM, FFN_DIM, FFN_DIM, rB, cB, lane, acc);
            #pragma unroll
            for (int mt = 0; mt < 2; mt++)
                #pragma unroll
                for (int nt = 0; nt < 2; nt++) {
                    int col = cB + nt*16 + cc;
                    float bv = ff2_b[l*HDIM + col];
                    #pragma unroll
                    for (int r = 0; r < 4; r++) {
                        int row = rB + mt*16 + quad*4 + r;
                        h[(size_t)row * HDIM + col] += acc[mt][nt][r] + bv;
                    }
                }
        }
        grid.sync();
    }

    // LNf
    ln_stage(h, lnf_g, lnf_b, xn, bid, wave, lane);
    grid.sync();

    // out = xn @ w_out^T + b_out  (fp32, 512 tiles)
    {
        int t = bid * 2 + grp;
        int rB = (t >> 2) * 64 + wm * 32, cB = (t & 3) * 64 + wn * 32;
        f32x4 acc[2][2];
        gemm_core((const short*)xn, (const short*)(wb + 65536), HDIM, HDIM, HDIM,
                  rB, cB, lane, acc);
        #pragma unroll
        for (int mt = 0; mt < 2; mt++)
            #pragma unroll
            for (int nt = 0; nt < 2; nt++) {
                int col = cB + nt*16 + cc;
                float bv = b_out[col];
                #pragma unroll
                for (int r = 0; r < 4; r++) {
                    int row = rB + mt*16 + quad*4 + r;
                    dout[(size_t)row * HDIM + col] = acc[mt][nt][r] + bv;
                }
            }
    }
}

// ===========================================================================
// FALLBACK PATH (round-6 multi-launch) — used only if cooperative launch fails
// ===========================================================================
__global__ __launch_bounds__(256)
void cvt_all(const float* __restrict__ w_in, const float* __restrict__ w_out,
             const float* __restrict__ qkv_w, const float* __restrict__ out_w,
             const float* __restrict__ ff1_w, const float* __restrict__ ff2_w,
             const float* __restrict__ x,
             __hip_bfloat16* __restrict__ wb, __hip_bfloat16* __restrict__ xb)
{
    int i = blockIdx.x * 256 + threadIdx.x;
    if (i >= 573440) return;
    cvt_item((size_t)i * 8, w_in, w_out, qkv_w, out_w, ff1_w, ff2_w, x, wb, xb);
}

template<int MODE, int NT>
__global__ __launch_bounds__(256)
void gemm_ln(const float* __restrict__ h,
             const float* __restrict__ g, const float* __restrict__ bln,
             const __hip_bfloat16* __restrict__ W,
             const float* __restrict__ bias,
             __hip_bfloat16* __restrict__ obf, float* __restrict__ of32,
             int N, int ldw)
{
    constexpr int NTW = NT / 32;
    __shared__ __align__(16) short A_lds[128][280];
    int tid = threadIdx.x, wave = tid >> 6, lane = tid & 63;
    int wm = wave >> 1, wn = wave & 1;
    int rowBase = blockIdx.y * 128;
    int colBase = blockIdx.x * NT + wn * (NT / 2);
    {
        float4 gv = *(const float4*)(g + lane * 4);
        float4 bv = *(const float4*)(bln + lane * 4);
        for (int rr = 0; rr < 32; rr += 4) {
            float4 xv[4];
            #pragma unroll
            for (int u = 0; u < 4; u++)
                xv[u] = *(const float4*)(h + (size_t)(rowBase + wave*32 + rr + u)*HDIM + lane*4);
            #pragma unroll
            for (int u = 0; u < 4; u++) {
                float s = xv[u].x + xv[u].y + xv[u].z + xv[u].w;
                #pragma unroll
                for (int off = 32; off >= 1; off >>= 1) s += __shfl_xor(s, off);
                float mu = s * (1.0f/256.0f);
                float d0 = xv[u].x-mu, d1 = xv[u].y-mu, d2 = xv[u].z-mu, d3 = xv[u].w-mu;
                float v = d0*d0 + d1*d1 + d2*d2 + d3*d3;
                #pragma unroll
                for (int off = 32; off >= 1; off >>= 1) v += __shfl_xor(v, off);
                float rstd = rsqrtf(v * (1.0f/256.0f) + 1e-5f);
                union { short e[4]; uint2 w2; } o;
                o.e[0] = (short)__bfloat16_as_ushort(__float2bfloat16(d0*rstd*gv.x + bv.x));
                o.e[1] = (short)__bfloat16_as_ushort(__float2bfloat16(d1*rstd*gv.y + bv.y));
                o.e[2] = (short)__bfloat16_as_ushort(__float2bfloat16(d2*rstd*gv.z + bv.z));
                o.e[3] = (short)__bfloat16_as_ushort(__float2bfloat16(d3*rstd*gv.w + bv.w));
                *(uint2*)&A_lds[wave*32 + rr + u][lane*4] = o.w2;
            }
        }
    }
    __syncthreads();
    int lr = lane & 15, hi = lane >> 4;
    f32x4 acc[4][NTW];
    #pragma unroll
    for (int mt = 0; mt < 4; mt++)
        #pragma unroll
        for (int nt = 0; nt < NTW; nt++)
            acc[mt][nt] = (f32x4){0.f,0.f,0.f,0.f};
    #pragma unroll
    for (int k0 = 0; k0 < 256; k0 += 32) {
        bf16x8 af[4], bfr[NTW];
        #pragma unroll
        for (int mt = 0; mt < 4; mt++)
            af[mt] = *(const bf16x8*)&A_lds[wm*64 + mt*16 + lr][k0 + hi*8];
        #pragma unroll
        for (int nt = 0; nt < NTW; nt++)
            bfr[nt] = *(const bf16x8*)((const short*)W + (size_t)(colBase + nt*16 + lr)*ldw + k0 + hi*8);
        #pragma unroll
        for (int mt = 0; mt < 4; mt++)
            #pragma unroll
            for (int nt = 0; nt < NTW; nt++)
                acc[mt][nt] = __builtin_amdgcn_mfma_f32_16x16x32_bf16(af[mt], bfr[nt], acc[mt][nt], 0,0,0);
    }
    int cc = lane & 15, quad = lane >> 4;
    #pragma unroll
    for (int mt = 0; mt < 4; mt++)
        #pragma unroll
        for (int nt = 0; nt < NTW; nt++) {
            int col = colBase + nt*16 + cc;
            float bv = bias[col];
            #pragma unroll
            for (int r = 0; r < 4; r++) {
                int row = rowBase + wm*64 + mt*16 + quad*4 + r;
                float c = acc[mt][nt][r] + bv;
                if (MODE == 2) { c = fmaxf(c, 0.f); obf[(size_t)row*N + col] = __float2bfloat16(c); }
                else if (MODE == 4) { of32[(size_t)row*N + col] = c; }
                else {
                    int sec = col >> 8, hd = (col >> 6) & 3, d = col & 63;
                    size_t idx = (size_t)sec*2097152 + (size_t)(((row>>11)<<2)|hd)*131072
                               + (size_t)(row & (SEQ-1))*64 + d;
                    obf[idx] = __float2bfloat16(c);
                }
            }
        }
}

template<int MODE>
__global__ __launch_bounds__(256)
void gemm64(const __hip_bfloat16* __restrict__ A, const __hip_bfloat16* __restrict__ W,
            const float* __restrict__ bias, float* __restrict__ hbuf,
            int N, int Kslice, int lda, int ldw, float alpha)
{
    int tid = threadIdx.x, wave = tid >> 6, lane = tid & 63;
    int wm = wave >> 1, wn = wave & 1;
    int rB = blockIdx.y*64 + wm*32, cB = blockIdx.x*64 + wn*32;
    int kbase = blockIdx.z * Kslice;
    f32x4 acc[2][2];
    gemm_core((const short*)A + kbase, (const short*)W + kbase, lda, ldw, Kslice, rB, cB, lane, acc);
    int cc = lane & 15, quad = lane >> 4;
    #pragma unroll
    for (int mt = 0; mt < 2; mt++)
        #pragma unroll
        for (int nt = 0; nt < 2; nt++) {
            int col = cB + nt*16 + cc;
            float bv = (MODE == 3 && blockIdx.z == 0) ? bias[col] : 0.f;
            #pragma unroll
            for (int r = 0; r < 4; r++) {
                int row = rB + mt*16 + quad*4 + r;
                float c = acc[mt][nt][r];
                if (MODE == 0) {
                    int i2 = col & ~1;
                    float freq = __expf((float)i2 * (-9.210340371976184f / 256.0f));
                    float arg = (float)(row & (SEQ-1)) * freq;
                    float pe = (col & 1) ? __cosf(arg) : __sinf(arg);
                    hbuf[(size_t)row*HDIM + col] = alpha*c + pe;
                } else {
                    atomicAdd(&hbuf[(size_t)row*HDIM + col], c + bv);
                }
            }
        }
}

__global__ __launch_bounds__(256)
void attn_sep(const __hip_bfloat16* __restrict__ qkvd, __hip_bfloat16* __restrict__ o)
{
    __shared__ AttnLDS S;
    int tid = threadIdx.x;
    attn_tile((const short*)qkvd, o, blockIdx.y, blockIdx.x * 32, S,
              tid >> 6, tid & 63, tid);
}

// ===========================================================================
extern "C" void kernel_launch(void* const* d_in, const int* in_sizes, int n_in,
                              void* d_out, int out_size, void* d_ws, size_t ws_size,
                              hipStream_t stream)
{
    const float* x     = (const float*)d_in[0];
    const float* w_in  = (const float*)d_in[1];
    const float* w_out = (const float*)d_in[2];
    const float* b_out = (const float*)d_in[3];
    const float* qkv_w = (const float*)d_in[4];
    const float* qkv_b = (const float*)d_in[5];
    const float* out_w = (const float*)d_in[6];
    const float* out_b = (const float*)d_in[7];
    const float* ln1_g = (const float*)d_in[8];
    const float* ln1_b = (const float*)d_in[9];
    const float* ln2_g = (const float*)d_in[10];
    const float* ln2_b = (const float*)d_in[11];
    const float* ff1_w = (const float*)d_in[12];
    const float* ff1_b = (const float*)d_in[13];
    const float* ff2_w = (const float*)d_in[14];
    const float* ff2_b = (const float*)d_in[15];
    const float* lnf_g = (const float*)d_in[16];
    const float* lnf_b = (const float*)d_in[17];
    float* dout = (float*)d_out;
    char*  wsc  = (char*)d_ws;

    void* kargs[20] = {
        (void*)&x, (void*)&w_in, (void*)&w_out, (void*)&b_out,
        (void*)&qkv_w, (void*)&qkv_b, (void*)&out_w, (void*)&out_b,
        (void*)&ln1_g, (void*)&ln1_b, (void*)&ln2_g, (void*)&ln2_b,
        (void*)&ff1_w, (void*)&ff1_b, (void*)&ff2_w, (void*)&ff2_b,
        (void*)&lnf_g, (void*)&lnf_b, (void*)&dout, (void*)&wsc
    };

    hipError_t err = hipLaunchCooperativeKernel((const void*)mega, dim3(256), dim3(512),
                                                kargs, 0, stream);
    if (err == hipSuccess) return;

    // ---------------- fallback: multi-launch path ----------------
    float*          h    = (float*)wsc;
    __hip_bfloat16* xn   = (__hip_bfloat16*)(wsc + 8388608);
    __hip_bfloat16* qkvd = (__hip_bfloat16*)(wsc + 12582912);
    __hip_bfloat16* att  = (__hip_bfloat16*)(wsc + 25165824);
    __hip_bfloat16* ffb  = (__hip_bfloat16*)(wsc + 29360128);
    __hip_bfloat16* wb   = (__hip_bfloat16*)(wsc + 46137344);
    __hip_bfloat16* xb   = (__hip_bfloat16*)(wsc + 51118080);

    dim3 blk(256);
    cvt_all<<<(573440 + 255) / 256, blk, 0, stream>>>(w_in, w_out, qkv_w, out_w,
                                                      ff1_w, ff2_w, x, wb, xb);
    gemm64<0><<<dim3(4, 128), blk, 0, stream>>>(xb, wb, nullptr, h, HDIM, HDIM, HDIM, HDIM, 16.0f);
    for (int l = 0; l < 3; l++) {
        // LN1 fused qkv (head-split)
        gemm_ln<5, 128><<<dim3(6, 64), blk, 0, stream>>>(
            h, ln1_g + l*HDIM, ln1_b + l*HDIM,
            wb + 131072 + (size_t)l*768*HDIM, qkv_b + l*768, qkvd, nullptr, 768, HDIM);
        attn_sep<<<dim3(SEQ/32, BATCH*NHEAD), blk, 0, stream>>>(qkvd, att);
        gemm64<3><<<dim3(4, 128, 2), blk, 0, stream>>>(
            att, wb + 720896 + (size_t)l*HDIM*HDIM, out_b + l*HDIM, h, HDIM, 128, HDIM, HDIM, 0.f);
        gemm_ln<2, 128><<<dim3(8, 64), blk, 0, stream>>>(
            h, ln2_g + l*HDIM, ln2_b + l*HDIM,
            wb + 917504 + (size_t)l*FFN_DIM*HDIM, ff1_b + l*FFN_DIM, ffb, nullptr, FFN_DIM, HDIM);
        gemm64<3><<<dim3(4, 128, 2), blk, 0, stream>>>(
            ffb, wb + 1703936 + (size_t)l*HDIM*FFN_DIM, ff2_b + l*HDIM, h, HDIM, 512, FFN_DIM, FFN_DIM, 0.f);
    }
    gemm_ln<4, 64><<<dim3(4, 64), blk, 0, stream>>>(
        h, lnf_g, lnf_b, wb + 65536, b_out, nullptr, dout, HDIM, HDIM);
}

// Round 8
// 407.373 us; speedup vs baseline: 3.3429x; 3.3429x over previous
//
#include <hip/hip_runtime.h>
#include <hip/hip_bf16.h>
#include <math.h>

#define SEQ 2048
#define BATCH 4
#define HDIM 256
#define NHEAD 4
#define FFN_DIM 1024
#define MTOT (BATCH*SEQ)   // 8192
#define WIN 32

typedef __attribute__((ext_vector_type(8))) short bf16x8;
typedef __attribute__((ext_vector_type(4))) float f32x4;

// ---------------------------------------------------------------------------
// Fused f32 -> bf16 convert of all weights + x. One launch.
// Arena element offsets: w_in 0, w_out 65536, qkv_w 131072, out_w 720896,
// ff1_w 917504, ff2_w 1703936 (end 2490368). x (2097152 elems) -> xb.
// ---------------------------------------------------------------------------
__global__ __launch_bounds__(256)
void cvt_all(const float* __restrict__ w_in, const float* __restrict__ w_out,
             const float* __restrict__ qkv_w, const float* __restrict__ out_w,
             const float* __restrict__ ff1_w, const float* __restrict__ ff2_w,
             const float* __restrict__ x,
             __hip_bfloat16* __restrict__ wb, __hip_bfloat16* __restrict__ xb)
{
    int i = blockIdx.x * 256 + threadIdx.x;
    if (i >= 573440) return;
    size_t e = (size_t)i * 8;
    const float* src;
    __hip_bfloat16* dst;
    if (e < 720896) {
        if (e < 65536)       { src = w_in  + e;            dst = wb + e; }
        else if (e < 131072) { src = w_out + (e - 65536);  dst = wb + e; }
        else                 { src = qkv_w + (e - 131072); dst = wb + e; }
    } else if (e < 917504)   { src = out_w + (e - 720896); dst = wb + e; }
    else if (e < 1703936)    { src = ff1_w + (e - 917504); dst = wb + e; }
    else if (e < 2490368)    { src = ff2_w + (e - 1703936); dst = wb + e; }
    else                     { src = x + (e - 2490368);    dst = xb + (e - 2490368); }

    const float4* s4 = (const float4*)src;
    float4 a = s4[0], b = s4[1];
    union { bf16x8 v; __hip_bfloat16 el[8]; } u;
    u.el[0] = __float2bfloat16(a.x); u.el[1] = __float2bfloat16(a.y);
    u.el[2] = __float2bfloat16(a.z); u.el[3] = __float2bfloat16(a.w);
    u.el[4] = __float2bfloat16(b.x); u.el[5] = __float2bfloat16(b.y);
    u.el[6] = __float2bfloat16(b.z); u.el[7] = __float2bfloat16(b.w);
    *(bf16x8*)dst = u.v;
}

// ---------------------------------------------------------------------------
// LN-fused GEMM (round-5 proven): O[M,N] = LN(h)[M,256] @ W[N,256]^T + bias
// MODE 1: obf = bf16(C+bias)      MODE 2: obf = bf16(relu(C+bias))
// MODE 4: of32 = C + bias
// Block: 128 rows x NT cols, 4 waves 2x2; LDS A tile [128][280].
// ---------------------------------------------------------------------------
template<int MODE, int NT>
__global__ __launch_bounds__(256)
void gemm_ln(const float* __restrict__ h,
             const float* __restrict__ g, const float* __restrict__ bln,
             const __hip_bfloat16* __restrict__ W,
             const float* __restrict__ bias,
             __hip_bfloat16* __restrict__ obf, float* __restrict__ of32,
             int N, int ldw)
{
    constexpr int NTW = NT / 32;
    __shared__ __align__(16) short A_lds[128][280];

    int tid = threadIdx.x, wave = tid >> 6, lane = tid & 63;
    int wm = wave >> 1, wn = wave & 1;
    int rowBase = blockIdx.y * 128;
    int colBase = blockIdx.x * NT + wn * (NT / 2);

    {
        float4 gv = *(const float4*)(g + lane * 4);
        float4 bv = *(const float4*)(bln + lane * 4);
        for (int rr = 0; rr < 32; rr += 4) {
            float4 xv[4];
            #pragma unroll
            for (int u = 0; u < 4; u++)
                xv[u] = *(const float4*)(h + (size_t)(rowBase + wave*32 + rr + u)*HDIM + lane*4);
            #pragma unroll
            for (int u = 0; u < 4; u++) {
                float s = xv[u].x + xv[u].y + xv[u].z + xv[u].w;
                #pragma unroll
                for (int off = 32; off >= 1; off >>= 1) s += __shfl_xor(s, off);
                float mu = s * (1.0f/256.0f);
                float d0 = xv[u].x-mu, d1 = xv[u].y-mu, d2 = xv[u].z-mu, d3 = xv[u].w-mu;
                float v = d0*d0 + d1*d1 + d2*d2 + d3*d3;
                #pragma unroll
                for (int off = 32; off >= 1; off >>= 1) v += __shfl_xor(v, off);
                float rstd = rsqrtf(v * (1.0f/256.0f) + 1e-5f);
                union { short e[4]; uint2 w2; } o;
                o.e[0] = (short)__bfloat16_as_ushort(__float2bfloat16(d0*rstd*gv.x + bv.x));
                o.e[1] = (short)__bfloat16_as_ushort(__float2bfloat16(d1*rstd*gv.y + bv.y));
                o.e[2] = (short)__bfloat16_as_ushort(__float2bfloat16(d2*rstd*gv.z + bv.z));
                o.e[3] = (short)__bfloat16_as_ushort(__float2bfloat16(d3*rstd*gv.w + bv.w));
                *(uint2*)&A_lds[wave*32 + rr + u][lane*4] = o.w2;
            }
        }
    }
    __syncthreads();

    int lr = lane & 15, hi = lane >> 4;
    f32x4 acc[4][NTW];
    #pragma unroll
    for (int mt = 0; mt < 4; mt++)
        #pragma unroll
        for (int nt = 0; nt < NTW; nt++)
            acc[mt][nt] = (f32x4){0.f,0.f,0.f,0.f};

    #pragma unroll
    for (int k0 = 0; k0 < 256; k0 += 32) {
        bf16x8 af[4], bfr[NTW];
        #pragma unroll
        for (int mt = 0; mt < 4; mt++)
            af[mt] = *(const bf16x8*)&A_lds[wm*64 + mt*16 + lr][k0 + hi*8];
        #pragma unroll
        for (int nt = 0; nt < NTW; nt++)
            bfr[nt] = *(const bf16x8*)((const short*)W + (size_t)(colBase + nt*16 + lr)*ldw + k0 + hi*8);
        #pragma unroll
        for (int mt = 0; mt < 4; mt++)
            #pragma unroll
            for (int nt = 0; nt < NTW; nt++)
                acc[mt][nt] = __builtin_amdgcn_mfma_f32_16x16x32_bf16(af[mt], bfr[nt], acc[mt][nt], 0,0,0);
    }

    int cc = lane & 15, quad = lane >> 4;
    #pragma unroll
    for (int mt = 0; mt < 4; mt++)
        #pragma unroll
        for (int nt = 0; nt < NTW; nt++) {
            int col = colBase + nt*16 + cc;
            float bv = bias[col];
            #pragma unroll
            for (int r = 0; r < 4; r++) {
                int row = rowBase + wm*64 + mt*16 + quad*4 + r;
                float c = acc[mt][nt][r] + bv;
                if (MODE == 2) { c = fmaxf(c, 0.f); obf[(size_t)row*N + col] = __float2bfloat16(c); }
                else if (MODE == 4) { of32[(size_t)row*N + col] = c; }
                else { obf[(size_t)row*N + col] = __float2bfloat16(c); }
            }
        }
}

// ---------------------------------------------------------------------------
// Direct GEMM, 64x64 tile (round-5 proven). No LDS.
// MODE 0: hbuf = alpha*C + PE(row%SEQ,col);  MODE 3: hbuf += C + bias
// ---------------------------------------------------------------------------
template<int MODE>
__global__ __launch_bounds__(256)
void gemm64(const __hip_bfloat16* __restrict__ A,
            const __hip_bfloat16* __restrict__ W,
            const float* __restrict__ bias,
            float* __restrict__ hbuf,
            int N, int K, int lda, int ldw, float alpha)
{
    int tid = threadIdx.x, wave = tid >> 6, lane = tid & 63;
    int wm = wave >> 1, wn = wave & 1;
    int rowBase = blockIdx.y * 64 + wm * 32;
    int colBase = blockIdx.x * 64 + wn * 32;
    int lr = lane & 15, hi = lane >> 4;

    const short* pa = (const short*)A + (size_t)(rowBase + lr) * lda + hi * 8;
    const short* pb = (const short*)W + (size_t)(colBase + lr) * ldw + hi * 8;

    f32x4 acc[2][2];
    acc[0][0] = (f32x4){0.f,0.f,0.f,0.f}; acc[0][1] = (f32x4){0.f,0.f,0.f,0.f};
    acc[1][0] = (f32x4){0.f,0.f,0.f,0.f}; acc[1][1] = (f32x4){0.f,0.f,0.f,0.f};

    for (int k0 = 0; k0 < K; k0 += 32) {
        bf16x8 a0 = *(const bf16x8*)pa;
        bf16x8 a1 = *(const bf16x8*)(pa + (size_t)16 * lda);
        bf16x8 b0 = *(const bf16x8*)pb;
        bf16x8 b1 = *(const bf16x8*)(pb + (size_t)16 * ldw);
        acc[0][0] = __builtin_amdgcn_mfma_f32_16x16x32_bf16(a0, b0, acc[0][0], 0,0,0);
        acc[0][1] = __builtin_amdgcn_mfma_f32_16x16x32_bf16(a0, b1, acc[0][1], 0,0,0);
        acc[1][0] = __builtin_amdgcn_mfma_f32_16x16x32_bf16(a1, b0, acc[1][0], 0,0,0);
        acc[1][1] = __builtin_amdgcn_mfma_f32_16x16x32_bf16(a1, b1, acc[1][1], 0,0,0);
        pa += 32; pb += 32;
    }

    int cc = lane & 15, quad = lane >> 4;
    #pragma unroll
    for (int mt = 0; mt < 2; mt++)
        #pragma unroll
        for (int nt = 0; nt < 2; nt++) {
            int col = colBase + nt*16 + cc;
            float bv = (MODE == 3) ? bias[col] : 0.f;
            #pragma unroll
            for (int r = 0; r < 4; r++) {
                int row = rowBase + mt*16 + quad*4 + r;
                float c = acc[mt][nt][r];
                if (MODE == 0) {
                    int i2 = col & ~1;
                    float freq = __expf((float)i2 * (-9.210340371976184f / 256.0f));
                    float arg = (float)(row & (SEQ-1)) * freq;
                    float pe = (col & 1) ? __cosf(arg) : __sinf(arg);
                    hbuf[(size_t)row*HDIM + col] = alpha*c + pe;
                } else {
                    hbuf[(size_t)row*HDIM + col] += c + bv;
                }
            }
        }
}

// ---------------------------------------------------------------------------
// FUSED attention + projection + residual. Block = 512 thr (8 waves),
// one (batch, 32-query stripe). Grid (64, 4).
// Two 4-wave groups each run the proven attn tile for 2 heads (rounds),
// writing O into LDS att tile [32][264] (pad -> 2-way banks, free).
// Then all 8 waves: proj O[32,256] @ out_w^T, h += result + out_b.
// qkv layout: interleaved [B][S][768] (round-5 proven access pattern).
// ---------------------------------------------------------------------------
__global__ __launch_bounds__(512)
void attn_proj(const __hip_bfloat16* __restrict__ qkv,
               const __hip_bfloat16* __restrict__ ow,   // bf16 [256][256]
               const float* __restrict__ ob,
               float* __restrict__ h)
{
    struct AttnLDS {
        __align__(16) __hip_bfloat16 Vt[64][128];
        __align__(16) __hip_bfloat16 Pl[32][96];
        float sm[2][32], ss[2][32];
    };
    __shared__ AttnLDS asl[2];
    __shared__ __align__(16) short att_lds[32][264];

    int tid  = threadIdx.x;
    int wave = tid >> 6, lane = tid & 63;
    int grp  = wave >> 2, w4 = wave & 3, ltid = tid & 255;
    int b    = blockIdx.y, i0 = blockIdx.x * 32;
    int klo  = i0 - 32;

    int lr = lane & 15, hi = lane >> 4;
    int cc = lane & 15, quad = lane >> 4;

    // ---- 4 head-tiles: group grp handles heads (rnd*2 + grp) ----
    for (int rnd = 0; rnd < 2; rnd++) {
        int hd = rnd * 2 + grp;
        AttnLDS& S = asl[grp];
        const short* base = (const short*)qkv + (size_t)(b * SEQ) * 768 + hd * 64;
        int qh = w4 & 1, seg = w4 >> 1;
        int qoff = qh * 16 + quad * 4;

        { // stage V^T (swizzled)
            int m = ltid & 7, rlane = ltid >> 3, dpart = m * 8;
            #pragma unroll
            for (int rr = 0; rr < 3; rr++) {
                int row = rr * 32 + rlane;
                int j = klo + row;
                j = j < 0 ? 0 : (j > SEQ - 1 ? SEQ - 1 : j);
                union { bf16x8 v; short e[8]; } u;
                u.v = *(const bf16x8*)(base + (size_t)j * 768 + 512 + dpart);
                int colp = row ^ (m << 3);
                #pragma unroll
                for (int jj = 0; jj < 8; jj++)
                    *(short*)&S.Vt[dpart + jj][colp] = u.e[jj];
            }
        }

        // phase A: S = Q K^T / 8
        bf16x8 qf[2];
        #pragma unroll
        for (int ds = 0; ds < 2; ds++)
            qf[ds] = *(const bf16x8*)(base + (size_t)(i0 + qh*16 + lr) * 768 + ds*32 + hi*8);
        f32x4 sacc[3];
        #pragma unroll
        for (int t = 0; t < 3; t++) {
            int j = klo + seg * 48 + t * 16 + lr;
            j = j < 0 ? 0 : (j > SEQ - 1 ? SEQ - 1 : j);
            const short* kp = base + (size_t)j * 768 + 256 + hi * 8;
            bf16x8 k0 = *(const bf16x8*)kp;
            bf16x8 k1 = *(const bf16x8*)(kp + 32);
            f32x4 a = (f32x4){0.f,0.f,0.f,0.f};
            a = __builtin_amdgcn_mfma_f32_16x16x32_bf16(qf[0], k0, a, 0,0,0);
            a = __builtin_amdgcn_mfma_f32_16x16x32_bf16(qf[1], k1, a, 0,0,0);
            sacc[t] = a;
        }

        float s[3][4];
        #pragma unroll
        for (int t = 0; t < 3; t++) {
            int koff = seg * 48 + t * 16 + cc;
            int jj = klo + koff;
            #pragma unroll
            for (int r = 0; r < 4; r++) {
                int rel = koff - (qoff + r);
                bool ok = (jj >= 0) && (jj < SEQ) && (rel >= 0) && (rel <= 64);
                s[t][r] = ok ? sacc[t][r] * 0.125f : -1e30f;
            }
        }

        float mrow[4], srow[4];
        #pragma unroll
        for (int r = 0; r < 4; r++)
            mrow[r] = fmaxf(fmaxf(s[0][r], s[1][r]), s[2][r]);
        #pragma unroll
        for (int off = 8; off >= 1; off >>= 1)
            #pragma unroll
            for (int r = 0; r < 4; r++)
                mrow[r] = fmaxf(mrow[r], __shfl_xor(mrow[r], off));
        #pragma unroll
        for (int r = 0; r < 4; r++)
            srow[r] = __expf(s[0][r]-mrow[r]) + __expf(s[1][r]-mrow[r]) + __expf(s[2][r]-mrow[r]);
        #pragma unroll
        for (int off = 8; off >= 1; off >>= 1)
            #pragma unroll
            for (int r = 0; r < 4; r++)
                srow[r] += __shfl_xor(srow[r], off);
        if (cc == 0) {
            #pragma unroll
            for (int r = 0; r < 4; r++) { S.sm[seg][qoff+r] = mrow[r]; S.ss[seg][qoff+r] = srow[r]; }
        }
        __syncthreads();

        float Mr[4], inv[4];
        #pragma unroll
        for (int r = 0; r < 4; r++) {
            float m0 = S.sm[0][qoff+r], m1 = S.sm[1][qoff+r];
            float M = fmaxf(m0, m1);
            float dn = S.ss[0][qoff+r] * __expf(m0 - M) + S.ss[1][qoff+r] * __expf(m1 - M);
            Mr[r] = M; inv[r] = 1.0f / dn;
        }
        #pragma unroll
        for (int t = 0; t < 3; t++)
            #pragma unroll
            for (int r = 0; r < 4; r++)
                S.Pl[qoff+r][seg*48 + t*16 + cc] = __float2bfloat16(__expf(s[t][r]-Mr[r]) * inv[r]);
        __syncthreads();

        // phase B: O = P @ V  -> att_lds
        f32x4 oacc[2];
        oacc[0] = (f32x4){0.f,0.f,0.f,0.f}; oacc[1] = (f32x4){0.f,0.f,0.f,0.f};
        #pragma unroll
        for (int ks = 0; ks < 3; ks++) {
            int kk = ks * 32;
            bf16x8 pf = *(const bf16x8*)&S.Pl[qh*16 + lr][kk + hi*8];
            #pragma unroll
            for (int dt = 0; dt < 2; dt++) {
                int d = seg*32 + dt*16 + lr;
                int colb = (kk + hi*8) ^ (((d >> 3) & 7) << 3);
                bf16x8 vf = *(const bf16x8*)&S.Vt[d][colb];
                oacc[dt] = __builtin_amdgcn_mfma_f32_16x16x32_bf16(pf, vf, oacc[dt], 0,0,0);
            }
        }
        #pragma unroll
        for (int dt = 0; dt < 2; dt++) {
            int col = hd*64 + seg*32 + dt*16 + cc;
            #pragma unroll
            for (int r = 0; r < 4; r++)
                att_lds[qoff + r][col] =
                    (short)__bfloat16_as_ushort(__float2bfloat16(oacc[dt][r]));
        }
        __syncthreads();
    }

    // ---- proj: O[32,256] @ ow^T + ob, h += ----
    int colBase = wave * 32;
    f32x4 acc[2][2];
    acc[0][0] = (f32x4){0.f,0.f,0.f,0.f}; acc[0][1] = (f32x4){0.f,0.f,0.f,0.f};
    acc[1][0] = (f32x4){0.f,0.f,0.f,0.f}; acc[1][1] = (f32x4){0.f,0.f,0.f,0.f};
    #pragma unroll
    for (int k0 = 0; k0 < 256; k0 += 32) {
        bf16x8 a0 = *(const bf16x8*)&att_lds[lr][k0 + hi*8];
        bf16x8 a1 = *(const bf16x8*)&att_lds[16 + lr][k0 + hi*8];
        bf16x8 b0 = *(const bf16x8*)((const short*)ow + (size_t)(colBase + lr)*HDIM + k0 + hi*8);
        bf16x8 b1 = *(const bf16x8*)((const short*)ow + (size_t)(colBase + 16 + lr)*HDIM + k0 + hi*8);
        acc[0][0] = __builtin_amdgcn_mfma_f32_16x16x32_bf16(a0, b0, acc[0][0], 0,0,0);
        acc[0][1] = __builtin_amdgcn_mfma_f32_16x16x32_bf16(a0, b1, acc[0][1], 0,0,0);
        acc[1][0] = __builtin_amdgcn_mfma_f32_16x16x32_bf16(a1, b0, acc[1][0], 0,0,0);
        acc[1][1] = __builtin_amdgcn_mfma_f32_16x16x32_bf16(a1, b1, acc[1][1], 0,0,0);
    }
    #pragma unroll
    for (int mt = 0; mt < 2; mt++)
        #pragma unroll
        for (int nt = 0; nt < 2; nt++) {
            int col = colBase + nt*16 + cc;
            float bv = ob[col];
            #pragma unroll
            for (int r = 0; r < 4; r++) {
                int row = b * SEQ + i0 + mt*16 + quad*4 + r;
                h[(size_t)row * HDIM + col] += acc[mt][nt][r] + bv;
            }
        }
}

// ---------------------------------------------------------------------------
extern "C" void kernel_launch(void* const* d_in, const int* in_sizes, int n_in,
                              void* d_out, int out_size, void* d_ws, size_t ws_size,
                              hipStream_t stream)
{
    const float* x     = (const float*)d_in[0];
    const float* w_in  = (const float*)d_in[1];
    const float* w_out = (const float*)d_in[2];
    const float* b_out = (const float*)d_in[3];
    const float* qkv_w = (const float*)d_in[4];
    const float* qkv_b = (const float*)d_in[5];
    const float* out_w = (const float*)d_in[6];
    const float* out_b = (const float*)d_in[7];
    const float* ln1_g = (const float*)d_in[8];
    const float* ln1_b = (const float*)d_in[9];
    const float* ln2_g = (const float*)d_in[10];
    const float* ln2_b = (const float*)d_in[11];
    const float* ff1_w = (const float*)d_in[12];
    const float* ff1_b = (const float*)d_in[13];
    const float* ff2_w = (const float*)d_in[14];
    const float* ff2_b = (const float*)d_in[15];
    const float* lnf_g = (const float*)d_in[16];
    const float* lnf_b = (const float*)d_in[17];

    char* ws = (char*)d_ws;
    float*          h    = (float*)ws;                        // [0, 8M)
    __hip_bfloat16* qkvb = (__hip_bfloat16*)(ws + 8388608);   // [8M, 20M) interleaved
    __hip_bfloat16* ffb  = (__hip_bfloat16*)(ws + 25165824);  // [24M, 40M)
    __hip_bfloat16* wb   = (__hip_bfloat16*)(ws + 41943040);  // weights bf16
    __hip_bfloat16* xb   = (__hip_bfloat16*)(ws + 46923776);  // x bf16

    __hip_bfloat16* w_in_b  = wb;
    __hip_bfloat16* w_out_b = wb + 65536;
    __hip_bfloat16* qkv_w_b = wb + 131072;
    __hip_bfloat16* out_w_b = wb + 720896;
    __hip_bfloat16* ff1_w_b = wb + 917504;
    __hip_bfloat16* ff2_w_b = wb + 1703936;

    dim3 blk(256);

    cvt_all<<<(573440 + 255) / 256, blk, 0, stream>>>(w_in, w_out, qkv_w, out_w,
                                                      ff1_w, ff2_w, x, wb, xb);

    // h = 16 * (x @ w_in^T) + PE
    gemm64<0><<<dim3(4, 128), blk, 0, stream>>>(xb, w_in_b, nullptr, h,
                                                HDIM, HDIM, HDIM, HDIM, 16.0f);

    for (int l = 0; l < 3; l++) {
        // qkv = LN1(h) @ qkv_w^T + qkv_b  (row-major interleaved [B,S,768])
        gemm_ln<1, 128><<<dim3(6, 64), blk, 0, stream>>>(
            h, ln1_g + l*HDIM, ln1_b + l*HDIM,
            qkv_w_b + (size_t)l*768*HDIM, qkv_b + l*768, qkvb, nullptr, 768, HDIM);
        // attention + projection + residual (fused)
        attn_proj<<<dim3(SEQ/32, BATCH), dim3(512), 0, stream>>>(
            qkvb, out_w_b + (size_t)l*HDIM*HDIM, out_b + l*HDIM, h);
        // ffb = relu(LN2(h) @ ff1_w^T + ff1_b)
        gemm_ln<2, 128><<<dim3(8, 64), blk, 0, stream>>>(
            h, ln2_g + l*HDIM, ln2_b + l*HDIM,
            ff1_w_b + (size_t)l*FFN_DIM*HDIM, ff1_b + l*FFN_DIM, ffb, nullptr, FFN_DIM, HDIM);
        // h += ffb @ ff2_w^T + ff2_b
        gemm64<3><<<dim3(4, 128), blk, 0, stream>>>(
            ffb, ff2_w_b + (size_t)l*HDIM*FFN_DIM, ff2_b + l*HDIM, h,
            HDIM, FFN_DIM, FFN_DIM, FFN_DIM, 0.f);
    }

    // out = LNf(h) @ w_out^T + b_out   (fp32)
    gemm_ln<4, 64><<<dim3(4, 64), blk, 0, stream>>>(
        h, lnf_g, lnf_b, w_out_b, b_out, nullptr, (float*)d_out, HDIM, HDIM);
}

// Round 9
// 404.693 us; speedup vs baseline: 3.3651x; 1.0066x over previous
//
#include <hip/hip_runtime.h>
#include <hip/hip_bf16.h>
#include <math.h>

#define SEQ 2048
#define BATCH 4
#define HDIM 256
#define NHEAD 4
#define FFN_DIM 1024
#define MTOT (BATCH*SEQ)   // 8192
#define WIN 32

typedef __attribute__((ext_vector_type(8))) short bf16x8;
typedef __attribute__((ext_vector_type(4))) float f32x4;

// ---------------------------------------------------------------------------
// Fused f32 -> bf16 convert of all weights + x. One launch.
// ---------------------------------------------------------------------------
__global__ __launch_bounds__(256)
void cvt_all(const float* __restrict__ w_in, const float* __restrict__ w_out,
             const float* __restrict__ qkv_w, const float* __restrict__ out_w,
             const float* __restrict__ ff1_w, const float* __restrict__ ff2_w,
             const float* __restrict__ x,
             __hip_bfloat16* __restrict__ wb, __hip_bfloat16* __restrict__ xb)
{
    int i = blockIdx.x * 256 + threadIdx.x;
    if (i >= 573440) return;
    size_t e = (size_t)i * 8;
    const float* src;
    __hip_bfloat16* dst;
    if (e < 720896) {
        if (e < 65536)       { src = w_in  + e;            dst = wb + e; }
        else if (e < 131072) { src = w_out + (e - 65536);  dst = wb + e; }
        else                 { src = qkv_w + (e - 131072); dst = wb + e; }
    } else if (e < 917504)   { src = out_w + (e - 720896); dst = wb + e; }
    else if (e < 1703936)    { src = ff1_w + (e - 917504); dst = wb + e; }
    else if (e < 2490368)    { src = ff2_w + (e - 1703936); dst = wb + e; }
    else                     { src = x + (e - 2490368);    dst = xb + (e - 2490368); }

    const float4* s4 = (const float4*)src;
    float4 a = s4[0], b = s4[1];
    union { bf16x8 v; __hip_bfloat16 el[8]; } u;
    u.el[0] = __float2bfloat16(a.x); u.el[1] = __float2bfloat16(a.y);
    u.el[2] = __float2bfloat16(a.z); u.el[3] = __float2bfloat16(a.w);
    u.el[4] = __float2bfloat16(b.x); u.el[5] = __float2bfloat16(b.y);
    u.el[6] = __float2bfloat16(b.z); u.el[7] = __float2bfloat16(b.w);
    *(bf16x8*)dst = u.v;
}

// ---------------------------------------------------------------------------
// LN-fused GEMM: O[M,N] = LN(h)[M,256] @ W[N,256]^T + bias
// MODE 2: obf = bf16(relu(C+bias))   MODE 4: of32 = C + bias
// MODE 5: head-split dense qkv write: bf16(C+bias) -> dst[sec][b*4+h][s][64]
//         sec = col>>8 (stride 2097152 elems), bh stride 131072.
// ---------------------------------------------------------------------------
template<int MODE, int NT>
__global__ __launch_bounds__(256)
void gemm_ln(const float* __restrict__ h,
             const float* __restrict__ g, const float* __restrict__ bln,
             const __hip_bfloat16* __restrict__ W,
             const float* __restrict__ bias,
             __hip_bfloat16* __restrict__ obf, float* __restrict__ of32,
             int N, int ldw)
{
    constexpr int NTW = NT / 32;
    __shared__ __align__(16) short A_lds[128][280];

    int tid = threadIdx.x, wave = tid >> 6, lane = tid & 63;
    int wm = wave >> 1, wn = wave & 1;
    int rowBase = blockIdx.y * 128;
    int colBase = blockIdx.x * NT + wn * (NT / 2);

    {
        float4 gv = *(const float4*)(g + lane * 4);
        float4 bv = *(const float4*)(bln + lane * 4);
        for (int rr = 0; rr < 32; rr += 4) {
            float4 xv[4];
            #pragma unroll
            for (int u = 0; u < 4; u++)
                xv[u] = *(const float4*)(h + (size_t)(rowBase + wave*32 + rr + u)*HDIM + lane*4);
            #pragma unroll
            for (int u = 0; u < 4; u++) {
                float s = xv[u].x + xv[u].y + xv[u].z + xv[u].w;
                #pragma unroll
                for (int off = 32; off >= 1; off >>= 1) s += __shfl_xor(s, off);
                float mu = s * (1.0f/256.0f);
                float d0 = xv[u].x-mu, d1 = xv[u].y-mu, d2 = xv[u].z-mu, d3 = xv[u].w-mu;
                float v = d0*d0 + d1*d1 + d2*d2 + d3*d3;
                #pragma unroll
                for (int off = 32; off >= 1; off >>= 1) v += __shfl_xor(v, off);
                float rstd = rsqrtf(v * (1.0f/256.0f) + 1e-5f);
                union { short e[4]; uint2 w2; } o;
                o.e[0] = (short)__bfloat16_as_ushort(__float2bfloat16(d0*rstd*gv.x + bv.x));
                o.e[1] = (short)__bfloat16_as_ushort(__float2bfloat16(d1*rstd*gv.y + bv.y));
                o.e[2] = (short)__bfloat16_as_ushort(__float2bfloat16(d2*rstd*gv.z + bv.z));
                o.e[3] = (short)__bfloat16_as_ushort(__float2bfloat16(d3*rstd*gv.w + bv.w));
                *(uint2*)&A_lds[wave*32 + rr + u][lane*4] = o.w2;
            }
        }
    }
    __syncthreads();

    int lr = lane & 15, hi = lane >> 4;
    f32x4 acc[4][NTW];
    #pragma unroll
    for (int mt = 0; mt < 4; mt++)
        #pragma unroll
        for (int nt = 0; nt < NTW; nt++)
            acc[mt][nt] = (f32x4){0.f,0.f,0.f,0.f};

    #pragma unroll
    for (int k0 = 0; k0 < 256; k0 += 32) {
        bf16x8 af[4], bfr[NTW];
        #pragma unroll
        for (int mt = 0; mt < 4; mt++)
            af[mt] = *(const bf16x8*)&A_lds[wm*64 + mt*16 + lr][k0 + hi*8];
        #pragma unroll
        for (int nt = 0; nt < NTW; nt++)
            bfr[nt] = *(const bf16x8*)((const short*)W + (size_t)(colBase + nt*16 + lr)*ldw + k0 + hi*8);
        #pragma unroll
        for (int mt = 0; mt < 4; mt++)
            #pragma unroll
            for (int nt = 0; nt < NTW; nt++)
                acc[mt][nt] = __builtin_amdgcn_mfma_f32_16x16x32_bf16(af[mt], bfr[nt], acc[mt][nt], 0,0,0);
    }

    int cc = lane & 15, quad = lane >> 4;
    #pragma unroll
    for (int mt = 0; mt < 4; mt++)
        #pragma unroll
        for (int nt = 0; nt < NTW; nt++) {
            int col = colBase + nt*16 + cc;
            float bv = bias[col];
            #pragma unroll
            for (int r = 0; r < 4; r++) {
                int row = rowBase + wm*64 + mt*16 + quad*4 + r;
                float c = acc[mt][nt][r] + bv;
                if (MODE == 2) { c = fmaxf(c, 0.f); obf[(size_t)row*N + col] = __float2bfloat16(c); }
                else if (MODE == 4) { of32[(size_t)row*N + col] = c; }
                else { // MODE 5: head-split dense qkv
                    int sec = col >> 8, hd = (col >> 6) & 3, d = col & 63;
                    size_t idx = (size_t)sec * 2097152
                               + (size_t)(((row >> 11) << 2) | hd) * 131072
                               + (size_t)(row & (SEQ - 1)) * 64 + d;
                    obf[idx] = __float2bfloat16(c);
                }
            }
        }
}

// ---------------------------------------------------------------------------
// Direct GEMM, 64x64 tile. No LDS.
// MODE 0: hbuf = alpha*C + PE(row%SEQ,col);  MODE 3: hbuf += C + bias
// ---------------------------------------------------------------------------
template<int MODE>
__global__ __launch_bounds__(256)
void gemm64(const __hip_bfloat16* __restrict__ A,
            const __hip_bfloat16* __restrict__ W,
            const float* __restrict__ bias,
            float* __restrict__ hbuf,
            int N, int K, int lda, int ldw, float alpha)
{
    int tid = threadIdx.x, wave = tid >> 6, lane = tid & 63;
    int wm = wave >> 1, wn = wave & 1;
    int rowBase = blockIdx.y * 64 + wm * 32;
    int colBase = blockIdx.x * 64 + wn * 32;
    int lr = lane & 15, hi = lane >> 4;

    const short* pa = (const short*)A + (size_t)(rowBase + lr) * lda + hi * 8;
    const short* pb = (const short*)W + (size_t)(colBase + lr) * ldw + hi * 8;

    f32x4 acc[2][2];
    acc[0][0] = (f32x4){0.f,0.f,0.f,0.f}; acc[0][1] = (f32x4){0.f,0.f,0.f,0.f};
    acc[1][0] = (f32x4){0.f,0.f,0.f,0.f}; acc[1][1] = (f32x4){0.f,0.f,0.f,0.f};

    #pragma unroll 4
    for (int k0 = 0; k0 < K; k0 += 32) {
        bf16x8 a0 = *(const bf16x8*)pa;
        bf16x8 a1 = *(const bf16x8*)(pa + (size_t)16 * lda);
        bf16x8 b0 = *(const bf16x8*)pb;
        bf16x8 b1 = *(const bf16x8*)(pb + (size_t)16 * ldw);
        acc[0][0] = __builtin_amdgcn_mfma_f32_16x16x32_bf16(a0, b0, acc[0][0], 0,0,0);
        acc[0][1] = __builtin_amdgcn_mfma_f32_16x16x32_bf16(a0, b1, acc[0][1], 0,0,0);
        acc[1][0] = __builtin_amdgcn_mfma_f32_16x16x32_bf16(a1, b0, acc[1][0], 0,0,0);
        acc[1][1] = __builtin_amdgcn_mfma_f32_16x16x32_bf16(a1, b1, acc[1][1], 0,0,0);
        pa += 32; pb += 32;
    }

    int cc = lane & 15, quad = lane >> 4;
    #pragma unroll
    for (int mt = 0; mt < 2; mt++)
        #pragma unroll
        for (int nt = 0; nt < 2; nt++) {
            int col = colBase + nt*16 + cc;
            float bv = (MODE == 3) ? bias[col] : 0.f;
            #pragma unroll
            for (int r = 0; r < 4; r++) {
                int row = rowBase + mt*16 + quad*4 + r;
                float c = acc[mt][nt][r];
                if (MODE == 0) {
                    int i2 = col & ~1;
                    float freq = __expf((float)i2 * (-9.210340371976184f / 256.0f));
                    float arg = (float)(row & (SEQ-1)) * freq;
                    float pe = (col & 1) ? __cosf(arg) : __sinf(arg);
                    hbuf[(size_t)row*HDIM + col] = alpha*c + pe;
                } else {
                    hbuf[(size_t)row*HDIM + col] += c + bv;
                }
            }
        }
}

// ---------------------------------------------------------------------------
// FUSED attention + projection + residual, on HEAD-SPLIT DENSE Q/K/V
// (qkvd[sec][b*4+h][s][64]; sec stride 2097152, bh stride 131072 elems).
// Block = 512 thr (8 waves), one (batch, 32-query stripe). Grid (64, 4).
// Group grp handles heads (rnd*2+grp); O -> LDS att tile [32][264];
// then all 8 waves: proj O[32,256] @ out_w^T, h += result + out_b.
// ---------------------------------------------------------------------------
__global__ __launch_bounds__(512)
void attn_proj(const __hip_bfloat16* __restrict__ qkvd,
               const __hip_bfloat16* __restrict__ ow,   // bf16 [256][256]
               const float* __restrict__ ob,
               float* __restrict__ h)
{
    struct AttnLDS {
        __align__(16) __hip_bfloat16 Vt[64][128];
        __align__(16) __hip_bfloat16 Pl[32][96];
        float sm[2][32], ss[2][32];
    };
    __shared__ AttnLDS asl[2];
    __shared__ __align__(16) short att_lds[32][264];

    int tid  = threadIdx.x;
    int wave = tid >> 6, lane = tid & 63;
    int grp  = wave >> 2, w4 = wave & 3, ltid = tid & 255;
    int b    = blockIdx.y, i0 = blockIdx.x * 32;
    int klo  = i0 - 32;

    int lr = lane & 15, hi = lane >> 4;
    int cc = lane & 15, quad = lane >> 4;

    for (int rnd = 0; rnd < 2; rnd++) {
        int hd = rnd * 2 + grp;
        AttnLDS& S = asl[grp];
        const short* Qd = (const short*)qkvd + (size_t)(b * 4 + hd) * 131072;
        const short* Kd = Qd + 2097152;
        const short* Vd = Qd + 4194304;
        int qh = w4 & 1, seg = w4 >> 1;
        int qoff = qh * 16 + quad * 4;

        { // stage V^T (fully coalesced dense reads, swizzled writes)
            int m = ltid & 7, rlane = ltid >> 3, dpart = m * 8;
            #pragma unroll
            for (int rr = 0; rr < 3; rr++) {
                int row = rr * 32 + rlane;
                int j = klo + row;
                j = j < 0 ? 0 : (j > SEQ - 1 ? SEQ - 1 : j);
                union { bf16x8 v; short e[8]; } u;
                u.v = *(const bf16x8*)(Vd + (size_t)j * 64 + dpart);
                int colp = row ^ (m << 3);
                #pragma unroll
                for (int jj = 0; jj < 8; jj++)
                    *(short*)&S.Vt[dpart + jj][colp] = u.e[jj];
            }
        }

        // phase A: S = Q K^T / 8 (dense 2KB-window fragment loads)
        bf16x8 qf[2];
        #pragma unroll
        for (int ds = 0; ds < 2; ds++)
            qf[ds] = *(const bf16x8*)(Qd + (size_t)(i0 + qh*16 + lr) * 64 + ds*32 + hi*8);
        f32x4 sacc[3];
        #pragma unroll
        for (int t = 0; t < 3; t++) {
            int j = klo + seg * 48 + t * 16 + lr;
            j = j < 0 ? 0 : (j > SEQ - 1 ? SEQ - 1 : j);
            const short* kp = Kd + (size_t)j * 64 + hi * 8;
            bf16x8 k0 = *(const bf16x8*)kp;
            bf16x8 k1 = *(const bf16x8*)(kp + 32);
            f32x4 a = (f32x4){0.f,0.f,0.f,0.f};
            a = __builtin_amdgcn_mfma_f32_16x16x32_bf16(qf[0], k0, a, 0,0,0);
            a = __builtin_amdgcn_mfma_f32_16x16x32_bf16(qf[1], k1, a, 0,0,0);
            sacc[t] = a;
        }

        float s[3][4];
        #pragma unroll
        for (int t = 0; t < 3; t++) {
            int koff = seg * 48 + t * 16 + cc;
            int jj = klo + koff;
            #pragma unroll
            for (int r = 0; r < 4; r++) {
                int rel = koff - (qoff + r);
                bool ok = (jj >= 0) && (jj < SEQ) && (rel >= 0) && (rel <= 64);
                s[t][r] = ok ? sacc[t][r] * 0.125f : -1e30f;
            }
        }

        float mrow[4], srow[4];
        #pragma unroll
        for (int r = 0; r < 4; r++)
            mrow[r] = fmaxf(fmaxf(s[0][r], s[1][r]), s[2][r]);
        #pragma unroll
        for (int off = 8; off >= 1; off >>= 1)
            #pragma unroll
            for (int r = 0; r < 4; r++)
                mrow[r] = fmaxf(mrow[r], __shfl_xor(mrow[r], off));
        #pragma unroll
        for (int r = 0; r < 4; r++)
            srow[r] = __expf(s[0][r]-mrow[r]) + __expf(s[1][r]-mrow[r]) + __expf(s[2][r]-mrow[r]);
        #pragma unroll
        for (int off = 8; off >= 1; off >>= 1)
            #pragma unroll
            for (int r = 0; r < 4; r++)
                srow[r] += __shfl_xor(srow[r], off);
        if (cc == 0) {
            #pragma unroll
            for (int r = 0; r < 4; r++) { S.sm[seg][qoff+r] = mrow[r]; S.ss[seg][qoff+r] = srow[r]; }
        }
        __syncthreads();

        float Mr[4], inv[4];
        #pragma unroll
        for (int r = 0; r < 4; r++) {
            float m0 = S.sm[0][qoff+r], m1 = S.sm[1][qoff+r];
            float M = fmaxf(m0, m1);
            float dn = S.ss[0][qoff+r] * __expf(m0 - M) + S.ss[1][qoff+r] * __expf(m1 - M);
            Mr[r] = M; inv[r] = 1.0f / dn;
        }
        #pragma unroll
        for (int t = 0; t < 3; t++)
            #pragma unroll
            for (int r = 0; r < 4; r++)
                S.Pl[qoff+r][seg*48 + t*16 + cc] = __float2bfloat16(__expf(s[t][r]-Mr[r]) * inv[r]);
        __syncthreads();

        // phase B: O = P @ V  -> att_lds
        f32x4 oacc[2];
        oacc[0] = (f32x4){0.f,0.f,0.f,0.f}; oacc[1] = (f32x4){0.f,0.f,0.f,0.f};
        #pragma unroll
        for (int ks = 0; ks < 3; ks++) {
            int kk = ks * 32;
            bf16x8 pf = *(const bf16x8*)&S.Pl[qh*16 + lr][kk + hi*8];
            #pragma unroll
            for (int dt = 0; dt < 2; dt++) {
                int d = seg*32 + dt*16 + lr;
                int colb = (kk + hi*8) ^ (((d >> 3) & 7) << 3);
                bf16x8 vf = *(const bf16x8*)&S.Vt[d][colb];
                oacc[dt] = __builtin_amdgcn_mfma_f32_16x16x32_bf16(pf, vf, oacc[dt], 0,0,0);
            }
        }
        #pragma unroll
        for (int dt = 0; dt < 2; dt++) {
            int col = hd*64 + seg*32 + dt*16 + cc;
            #pragma unroll
            for (int r = 0; r < 4; r++)
                att_lds[qoff + r][col] =
                    (short)__bfloat16_as_ushort(__float2bfloat16(oacc[dt][r]));
        }
        __syncthreads();
    }

    // ---- proj: O[32,256] @ ow^T + ob, h += ----
    int colBase = wave * 32;
    f32x4 acc[2][2];
    acc[0][0] = (f32x4){0.f,0.f,0.f,0.f}; acc[0][1] = (f32x4){0.f,0.f,0.f,0.f};
    acc[1][0] = (f32x4){0.f,0.f,0.f,0.f}; acc[1][1] = (f32x4){0.f,0.f,0.f,0.f};
    #pragma unroll
    for (int k0 = 0; k0 < 256; k0 += 32) {
        bf16x8 a0 = *(const bf16x8*)&att_lds[lr][k0 + hi*8];
        bf16x8 a1 = *(const bf16x8*)&att_lds[16 + lr][k0 + hi*8];
        bf16x8 b0 = *(const bf16x8*)((const short*)ow + (size_t)(colBase + lr)*HDIM + k0 + hi*8);
        bf16x8 b1 = *(const bf16x8*)((const short*)ow + (size_t)(colBase + 16 + lr)*HDIM + k0 + hi*8);
        acc[0][0] = __builtin_amdgcn_mfma_f32_16x16x32_bf16(a0, b0, acc[0][0], 0,0,0);
        acc[0][1] = __builtin_amdgcn_mfma_f32_16x16x32_bf16(a0, b1, acc[0][1], 0,0,0);
        acc[1][0] = __builtin_amdgcn_mfma_f32_16x16x32_bf16(a1, b0, acc[1][0], 0,0,0);
        acc[1][1] = __builtin_amdgcn_mfma_f32_16x16x32_bf16(a1, b1, acc[1][1], 0,0,0);
    }
    #pragma unroll
    for (int mt = 0; mt < 2; mt++)
        #pragma unroll
        for (int nt = 0; nt < 2; nt++) {
            int col = colBase + nt*16 + cc;
            float bv = ob[col];
            #pragma unroll
            for (int r = 0; r < 4; r++) {
                int row = b * SEQ + i0 + mt*16 + quad*4 + r;
                h[(size_t)row * HDIM + col] += acc[mt][nt][r] + bv;
            }
        }
}

// ---------------------------------------------------------------------------
extern "C" void kernel_launch(void* const* d_in, const int* in_sizes, int n_in,
                              void* d_out, int out_size, void* d_ws, size_t ws_size,
                              hipStream_t stream)
{
    const float* x     = (const float*)d_in[0];
    const float* w_in  = (const float*)d_in[1];
    const float* w_out = (const float*)d_in[2];
    const float* b_out = (const float*)d_in[3];
    const float* qkv_w = (const float*)d_in[4];
    const float* qkv_b = (const float*)d_in[5];
    const float* out_w = (const float*)d_in[6];
    const float* out_b = (const float*)d_in[7];
    const float* ln1_g = (const float*)d_in[8];
    const float* ln1_b = (const float*)d_in[9];
    const float* ln2_g = (const float*)d_in[10];
    const float* ln2_b = (const float*)d_in[11];
    const float* ff1_w = (const float*)d_in[12];
    const float* ff1_b = (const float*)d_in[13];
    const float* ff2_w = (const float*)d_in[14];
    const float* ff2_b = (const float*)d_in[15];
    const float* lnf_g = (const float*)d_in[16];
    const float* lnf_b = (const float*)d_in[17];

    char* ws = (char*)d_ws;
    float*          h    = (float*)ws;                        // [0, 8M)
    __hip_bfloat16* qkvd = (__hip_bfloat16*)(ws + 8388608);   // [8M, 20.97M) head-split dense
    __hip_bfloat16* ffb  = (__hip_bfloat16*)(ws + 25165824);  // [24M, 40M)
    __hip_bfloat16* wb   = (__hip_bfloat16*)(ws + 41943040);  // weights bf16
    __hip_bfloat16* xb   = (__hip_bfloat16*)(ws + 46923776);  // x bf16

    __hip_bfloat16* w_in_b  = wb;
    __hip_bfloat16* w_out_b = wb + 65536;
    __hip_bfloat16* qkv_w_b = wb + 131072;
    __hip_bfloat16* out_w_b = wb + 720896;
    __hip_bfloat16* ff1_w_b = wb + 917504;
    __hip_bfloat16* ff2_w_b = wb + 1703936;

    dim3 blk(256);

    cvt_all<<<(573440 + 255) / 256, blk, 0, stream>>>(w_in, w_out, qkv_w, out_w,
                                                      ff1_w, ff2_w, x, wb, xb);

    // h = 16 * (x @ w_in^T) + PE
    gemm64<0><<<dim3(4, 128), blk, 0, stream>>>(xb, w_in_b, nullptr, h,
                                                HDIM, HDIM, HDIM, HDIM, 16.0f);

    for (int l = 0; l < 3; l++) {
        // qkv (head-split dense) = LN1(h) @ qkv_w^T + qkv_b
        gemm_ln<5, 128><<<dim3(6, 64), blk, 0, stream>>>(
            h, ln1_g + l*HDIM, ln1_b + l*HDIM,
            qkv_w_b + (size_t)l*768*HDIM, qkv_b + l*768, qkvd, nullptr, 768, HDIM);
        // attention + projection + residual (fused, dense layout)
        attn_proj<<<dim3(SEQ/32, BATCH), dim3(512), 0, stream>>>(
            qkvd, out_w_b + (size_t)l*HDIM*HDIM, out_b + l*HDIM, h);
        // ffb = relu(LN2(h) @ ff1_w^T + ff1_b)
        gemm_ln<2, 128><<<dim3(8, 64), blk, 0, stream>>>(
            h, ln2_g + l*HDIM, ln2_b + l*HDIM,
            ff1_w_b + (size_t)l*FFN_DIM*HDIM, ff1_b + l*FFN_DIM, ffb, nullptr, FFN_DIM, HDIM);
        // h += ffb @ ff2_w^T + ff2_b
        gemm64<3><<<dim3(4, 128), blk, 0, stream>>>(
            ffb, ff2_w_b + (size_t)l*HDIM*FFN_DIM, ff2_b + l*HDIM, h,
            HDIM, FFN_DIM, FFN_DIM, FFN_DIM, 0.f);
    }

    // out = LNf(h) @ w_out^T + b_out   (fp32)
    gemm_ln<4, 64><<<dim3(4, 64), blk, 0, stream>>>(
        h, lnf_g, lnf_b, w_out_b, b_out, nullptr, (float*)d_out, HDIM, HDIM);
}